// Round 10
// baseline (193.812 us; speedup 1.0000x reference)
//
#include <hip/hip_runtime.h>
#include <math.h>

#define B_ 8
#define T_ 2048
#define F_ 256
#define M_TOT (B_ * T_)   // 16384

typedef __attribute__((ext_vector_type(8))) short short8;
typedef __attribute__((ext_vector_type(4))) float floatx4;

// bf16 round-to-nearest-even helpers (finite inputs only)
__device__ __forceinline__ short f2bf(float x) {
    unsigned u = __float_as_uint(x);
    u += 0x7FFF + ((u >> 16) & 1);
    return (short)(u >> 16);
}
__device__ __forceinline__ float bf2f(short s) {
    return __uint_as_float(((unsigned)(unsigned short)s) << 16);
}

// async global -> LDS copy, 16 B per lane (gfx950 global_load_lds_dwordx4)
__device__ __forceinline__ void cp_g2l_16(const void* g, void* l) {
    __builtin_amdgcn_global_load_lds(
        (const __attribute__((address_space(1))) void*)g,
        (__attribute__((address_space(3))) void*)l, 16, 0, 0);
}

// ---------------------------------------------------------------------------
// Kernel 1: fused pre-pack. Blocks (0..63, b): one pass over feat producing
//  (a) PV B-fragments (hi) into the staged attn blocks (stg + 8192),
//  (b) per-(b,32-row-chunk) column sums (featpart, for kbar).
// R19: featAh/featAl section DELETED — proj now builds A-fragments itself
// from feat (bit-identical conversion), killing the 32 MB HBM round-trip.
// Blocks (64, g): pack Wq (hi+lo) / Wk (hi) into B-fragment order.
// ---------------------------------------------------------------------------
__global__ __launch_bounds__(256) void pack_feat_all(
    const float* __restrict__ feat,
    short* __restrict__ stg, float* __restrict__ featpart,
    const float* __restrict__ Wq, const float* __restrict__ Wk,
    short* __restrict__ wfqh, short* __restrict__ wfql,
    short* __restrict__ wfkh)
{
    const int tid = threadIdx.x;
    const int lane = tid & 63, w = tid >> 6;
    const int quad = lane >> 4, l15 = lane & 15;

    if (blockIdx.x == 64) {   // ---- W-pack blocks (8 x 256 thr) ----
#pragma unroll
        for (int i = 0; i < 8; ++i) {
            const int idx = blockIdx.y * 32 + w * 8 + i;   // 0..255
            const int isk = idx >> 7, nt = (idx >> 3) & 15, fc = idx & 7;
            const float* __restrict__ W = isk ? Wk : Wq;
            const int row = nt * 16 + l15, col = fc * 32 + quad * 8;
            float v[8];
            *(float4*)&v[0] = *(const float4*)&W[(size_t)row * F_ + col];
            *(float4*)&v[4] = *(const float4*)&W[(size_t)row * F_ + col + 4];
            const size_t dst = ((size_t)(nt * 8 + fc)) * 512 + lane * 8;
            if (isk) {
                short8 h;
#pragma unroll
                for (int j = 0; j < 8; ++j) h[j] = f2bf(v[j]);
                *(short8*)&wfkh[dst] = h;
            } else {
                short8 h, l;
#pragma unroll
                for (int j = 0; j < 8; ++j) {
                    const short hh = f2bf(v[j]);
                    h[j] = hh; l[j] = f2bf(v[j] - bf2f(hh));
                }
                *(short8*)&wfqh[dst] = h;
                *(short8*)&wfql[dst] = l;
            }
        }
        return;
    }

    __shared__ float lds[32][260];
    const int kc  = blockIdx.x;   // 0..63
    const int b   = blockIdx.y;

#pragma unroll
    for (int i = 0; i < 8; ++i) {
        const int lin = i * 256 + tid;
        const int r = lin >> 6, c4 = (lin & 63) * 4;
        float4 v = *(const float4*)&feat[((size_t)b * T_ + kc * 32 + r) * F_ + c4];
        lds[r][c4 + 0] = v.x; lds[r][c4 + 1] = v.y;
        lds[r][c4 + 2] = v.z; lds[r][c4 + 3] = v.w;
    }
    __syncthreads();

#pragma unroll
    for (int fi = 0; fi < 4; ++fi) {
        const int ft = w + fi * 4;
        short8 h;
#pragma unroll
        for (int j = 0; j < 8; ++j)
            h[j] = f2bf(lds[quad * 8 + j][ft * 16 + l15]);
        const size_t dst = ((size_t)(b * 64 + kc)) * 16384 + 8192 + ft * 512 + lane * 8;
        *(short8*)&stg[dst] = h;
    }

    {
        float s = 0.f;
#pragma unroll
        for (int r = 0; r < 32; ++r) s += lds[r][tid];
        featpart[((size_t)b * 64 + kc) * 256 + tid] = s;
    }
}

// ---------------------------------------------------------------------------
// Kernel 4: MFMA projection. R19: A-fragments built IN-KERNEL from feat via
// a chunked LDS transpose prologue (bit-identical f2bf hi/lo conversion to
// the old pack path) — featAh/featAl buffers eliminated. LDS is a union:
// fch (prologue) overlaps wbuf+Tr (main loop): 50 KB -> >=2 blocks/CU.
// XCD-coherent grid remap (R16) and the W-staged MFMA main loop unchanged.
// R18 wvec guard-blocks (x >= 512) unchanged.
// ---------------------------------------------------------------------------
struct ProjLDS {
    union {
        float fch[32][260];                       // prologue feat chunk
        struct { short wbuf[2][8192]; float Tr[8][16][36]; } m;
    } u;
};

__global__ __launch_bounds__(512, 2) void proj_mfma(
    const float* __restrict__ feat,
    const short* __restrict__ wfqh, const short* __restrict__ wfql,
    const short* __restrict__ wfkh,
    const float* __restrict__ bq, const float* __restrict__ bk,
    short* __restrict__ qfh, short* __restrict__ qfl,
    short* __restrict__ stg,
    const float* __restrict__ featpart, const float* __restrict__ Wk,
    float* __restrict__ kbar_g, float* __restrict__ out_hlens)
{
    __shared__ ProjLDS L;

    const int tid = threadIdx.x, lane = tid & 63, w = tid >> 6;
    const int quad = lane >> 4, l15 = lane & 15;
    const int x  = blockIdx.x;

    if (x >= 512) {   // ---- folded wvec blocks (8 x, only tid<256 active) --
        float* fb = (float*)L.u.m.wbuf;
        const int bb = x - 512;
        if (tid < 256) {
            float s = 0.f;
#pragma unroll 8
            for (int c = 0; c < 64; ++c)
                s += featpart[((size_t)bb * 64 + c) * 256 + tid];
            fb[tid] = s * (1.0f / (float)T_);
        }
        __syncthreads();
        if (tid < 256) {
            float acc = bk[tid];
#pragma unroll 8
            for (int f = 0; f < 256; ++f)
                acc += Wk[(size_t)tid * 256 + f] * fb[f];
            kbar_g[bb * 256 + tid] = acc;
        }
        if (bb == 0 && tid < B_) out_hlens[tid] = (float)T_;
        return;
    }

    const int ng = x >> 7, rg = x & 127;   // XCD-coherent remap
    const bool isq = ng < 2;
    const int r16 = rg * 8 + w;
    const int b = r16 >> 7, qt16 = r16 & 127;
    const int ntb = isq ? ng * 8 : (ng - 2) * 8;

    // ---- prologue: build ah/al from feat (chunked LDS transpose) ----------
    // chunk c covers rows (rg&15)*128 + c*32 .. +31 of batch b; waves 2c and
    // 2c+1 extract their 16 rows into registers (same math as old pack).
    short8 ah[8], al[8];
    const size_t rowbase = (size_t)b * T_ + (rg & 15) * 128;
#pragma unroll
    for (int c = 0; c < 4; ++c) {
        __syncthreads();   // previous chunk fully consumed
#pragma unroll
        for (int i = 0; i < 4; ++i) {
            const int lin = i * 512 + tid;
            const int r = lin >> 6, c4 = (lin & 63) * 4;
            float4 v = *(const float4*)&feat[(rowbase + c * 32 + r) * F_ + c4];
            L.u.fch[r][c4 + 0] = v.x; L.u.fch[r][c4 + 1] = v.y;
            L.u.fch[r][c4 + 2] = v.z; L.u.fch[r][c4 + 3] = v.w;
        }
        __syncthreads();
        if ((w >> 1) == c) {
            const int h = w & 1;
#pragma unroll
            for (int fc = 0; fc < 8; ++fc) {
                float v[8];
                *(float4*)&v[0] = *(const float4*)&L.u.fch[h * 16 + l15][fc * 32 + quad * 8];
                *(float4*)&v[4] = *(const float4*)&L.u.fch[h * 16 + l15][fc * 32 + quad * 8 + 4];
#pragma unroll
                for (int j = 0; j < 8; ++j) {
                    const short hh = f2bf(v[j]);
                    ah[fc][j] = hh; al[fc][j] = f2bf(v[j] - bf2f(hh));
                }
            }
        }
    }
    __syncthreads();   // fch dead; wbuf/Tr live from here

    const short* __restrict__ wsh = (isq ? wfqh : wfkh) + (size_t)ntb * 4096;
    const short* __restrict__ wsl = wfql + (size_t)ntb * 4096;
    const float* __restrict__ bias = isq ? bq : bk;

    cp_g2l_16(wsh + tid * 8, &L.u.m.wbuf[0][tid * 8]);
    if (isq) cp_g2l_16(wsl + tid * 8, &L.u.m.wbuf[0][4096 + tid * 8]);

    int cur = 0;
    for (int i = 0; i < 8; ++i, cur ^= 1) {
        __syncthreads();

        floatx4 C = (floatx4){0.f, 0.f, 0.f, 0.f};
#pragma unroll
        for (int fc = 0; fc < 8; ++fc) {
            short8 wh = *(const short8*)&L.u.m.wbuf[cur][fc * 512 + lane * 8];
            C = __builtin_amdgcn_mfma_f32_16x16x32_bf16(ah[fc], wh, C, 0, 0, 0);
            C = __builtin_amdgcn_mfma_f32_16x16x32_bf16(al[fc], wh, C, 0, 0, 0);
            if (isq) {
                short8 wl2 = *(const short8*)&L.u.m.wbuf[cur][4096 + fc * 512 + lane * 8];
                C = __builtin_amdgcn_mfma_f32_16x16x32_bf16(ah[fc], wl2, C, 0, 0, 0);
            }
        }

        if (i + 1 < 8) {
            cp_g2l_16(wsh + (size_t)(i + 1) * 4096 + tid * 8,
                      &L.u.m.wbuf[cur ^ 1][tid * 8]);
            if (isq) cp_g2l_16(wsl + (size_t)(i + 1) * 4096 + tid * 8,
                               &L.u.m.wbuf[cur ^ 1][4096 + tid * 8]);
        }

        const int nt = ntb + i;
        const float bv = bias[nt * 16 + l15];
        const int ch = (i & 1) * 16;
#pragma unroll
        for (int r = 0; r < 4; ++r)
            L.u.m.Tr[w][quad * 4 + r][ch + l15] = C[r] + bv;

        if (i & 1) {
            float v[8];
            *(float4*)&v[0] = *(const float4*)&L.u.m.Tr[w][l15][quad * 8];
            *(float4*)&v[4] = *(const float4*)&L.u.m.Tr[w][l15][quad * 8 + 4];
            const int p = nt >> 1;
            if (isq) {
                short8 h, l;
#pragma unroll
                for (int j = 0; j < 8; ++j) {
                    const short hh = f2bf(v[j]);
                    h[j] = hh; l[j] = f2bf(v[j] - bf2f(hh));
                }
                const size_t dst = ((size_t)(b * 8 + p) * 128 + qt16) * 512 + lane * 8;
                __builtin_nontemporal_store(h, (short8*)&qfh[dst]);
                __builtin_nontemporal_store(l, (short8*)&qfl[dst]);
            } else {
                short8 h;
#pragma unroll
                for (int j = 0; j < 8; ++j) h[j] = f2bf(v[j]);
                const size_t dst = ((size_t)(b * 64 + (qt16 >> 1))) * 16384
                                 + (p * 2 + (qt16 & 1)) * 512 + lane * 8;
                *(short8*)&stg[dst] = h;
            }
        }
    }
}

// ---------------------------------------------------------------------------
// Kernel 5: fused flash attention. Loop byte-identical to R10/R15/R16 (the
// 65.4 µs config) — every loop perturbation (R11-R14) regressed, and R17's
// fused combine thrashed L2. Epilogue has only the R16-proven score fusion.
// ---------------------------------------------------------------------------
__global__ __launch_bounds__(256, 2) void attn_mfma(
    const short* __restrict__ qfh_g, const short* __restrict__ qfl_g,
    const short* __restrict__ stg,
    float* __restrict__ o0, float* __restrict__ o1,
    float* __restrict__ lpart,
    const float* __restrict__ kbar_g, float* __restrict__ out_score)
{
    __shared__ short kbuf[2][16384];   // staged kt block: kf @0, ff @8192
    __shared__ float P_lds[64 * 36];   // [q][key], rows padded to 36 floats
    __shared__ float l_lds[2][64];     // [fh][q-row]

    const int tid  = threadIdx.x;
    const int wave = tid >> 6, lane = tid & 63;
    const int qp   = wave & 1, fh = wave >> 1;
    const int quad = lane >> 4, l15 = lane & 15;

    const int lid  = blockIdx.x;      // 0..511
    const int b    = lid & 7;         // XCD pin: batch -> XCD
    const int qt   = (lid >> 3) & 31;
    const int ks   = lid >> 8;

    // persistent Q fragments for TWO q-tiles (A-operand), hi/lo: 128 VGPRs
    short8 qh[2][8], ql[2][8];
#pragma unroll
    for (int t = 0; t < 2; ++t) {
        const int qt16 = qt * 4 + qp * 2 + t;
#pragma unroll
        for (int fc = 0; fc < 8; ++fc) {
            const size_t off = ((size_t)(b * 8 + fc) * 128 + qt16) * 512 + lane * 8;
            qh[t][fc] = *(const short8*)&qfh_g[off];
            ql[t][fc] = *(const short8*)&qfl_g[off];
        }
    }

    floatx4 O[2][8];
#pragma unroll
    for (int t = 0; t < 2; ++t)
#pragma unroll
        for (int i = 0; i < 8; ++i) O[t][i] = (floatx4){0.f, 0.f, 0.f, 0.f};
    float lsum[2][4] = {};

    const short* sbase = &stg[(size_t)b * 64 * 16384];
    const int kbeg = ks * 32, kend = kbeg + 32;

    {
        const short* src = sbase + (size_t)kbeg * 16384 + tid * 8;
        short* dst = &kbuf[0][tid * 8];
#pragma unroll
        for (int i = 0; i < 8; ++i)
            cp_g2l_16(src + i * 2048, dst + i * 2048);
    }

    int cur = 0;
    for (int kt = kbeg; kt < kend; ++kt, cur ^= 1) {
        __syncthreads();   // drains DMA for kbuf[cur]; P_lds readers done

        // ---- S: 2 q-tiles x this wave's 16-key half (slot = fh) ----------
        floatx4 Sa[2], Sb[2];
#pragma unroll
        for (int t = 0; t < 2; ++t) {
            Sa[t] = (floatx4){0.f, 0.f, 0.f, 0.f};
            Sb[t] = (floatx4){0.f, 0.f, 0.f, 0.f};
        }
#pragma unroll
        for (int fc = 0; fc < 8; ++fc) {
            short8 bh = *(const short8*)&kbuf[cur][(fc * 2 + fh) * 512 + lane * 8];
#pragma unroll
            for (int t = 0; t < 2; ++t) {
                Sa[t] = __builtin_amdgcn_mfma_f32_16x16x32_bf16(qh[t][fc], bh, Sa[t], 0, 0, 0);
                Sb[t] = __builtin_amdgcn_mfma_f32_16x16x32_bf16(ql[t][fc], bh, Sb[t], 0, 0, 0);
            }
        }

        // ---- exp (max-free) + write P [row][key] -------------------------
#pragma unroll
        for (int t = 0; t < 2; ++t)
#pragma unroll
            for (int r = 0; r < 4; ++r) {
                const float e = __expf(Sa[t][r] + Sb[t][r]);
                lsum[t][r] += e;
                P_lds[((qp * 2 + t) * 16 + quad * 4 + r) * 36 + fh * 16 + l15] = e;
            }
        __syncthreads();

        // ---- read P in A-layout (b128), convert to bf16 (hi only) --------
        short8 ph[2];
#pragma unroll
        for (int t = 0; t < 2; ++t) {
            float pv[8];
            *(float4*)&pv[0] = *(const float4*)&P_lds[((qp * 2 + t) * 16 + l15) * 36 + quad * 8];
            *(float4*)&pv[4] = *(const float4*)&P_lds[((qp * 2 + t) * 16 + l15) * 36 + quad * 8 + 4];
#pragma unroll
            for (int j = 0; j < 8; ++j)
                ph[t][j] = f2bf(pv[j]);
        }

        // ---- prefetch next kt into the other buffer (overlaps PV) --------
        if (kt + 1 < kend) {
            const short* src = sbase + (size_t)(kt + 1) * 16384 + tid * 8;
            short* dst = &kbuf[cur ^ 1][tid * 8];
#pragma unroll
            for (int i = 0; i < 8; ++i)
                cp_g2l_16(src + i * 2048, dst + i * 2048);
        }

        // ---- O += bf16(P) . fh  (2 q-tiles x wave's 128-f half) ----------
#pragma unroll
        for (int ft = 0; ft < 8; ++ft) {
            short8 fv = *(const short8*)&kbuf[cur][8192 + (fh * 8 + ft) * 512 + lane * 8];
#pragma unroll
            for (int t = 0; t < 2; ++t)
                O[t][ft] = __builtin_amdgcn_mfma_f32_16x16x32_bf16(ph[t], fv, O[t][ft], 0, 0, 0);
        }
    }

    // ---- score epilogue (ks==0 blocks): score[row] = (qh+ql) . kbar ------
    if (ks == 0) {
        const float* __restrict__ kb = &kbar_g[b * 256];
        float sc[2] = {0.f, 0.f};
#pragma unroll
        for (int fc = 0; fc < 8; ++fc) {
            float4 k0 = *(const float4*)&kb[fc * 32 + quad * 8];
            float4 k1 = *(const float4*)&kb[fc * 32 + quad * 8 + 4];
#pragma unroll
            for (int t = 0; t < 2; ++t) {
#pragma unroll
                for (int j = 0; j < 4; ++j) {
                    sc[t] += (bf2f(qh[t][fc][j]) + bf2f(ql[t][fc][j]))
                           * ((const float*)&k0)[j];
                    sc[t] += (bf2f(qh[t][fc][j + 4]) + bf2f(ql[t][fc][j + 4]))
                           * ((const float*)&k1)[j];
                }
            }
        }
#pragma unroll
        for (int t = 0; t < 2; ++t) {
            sc[t] += __shfl_xor(sc[t], 16, 64);
            sc[t] += __shfl_xor(sc[t], 32, 64);
            if (quad == 0)
                out_score[(size_t)b * T_ + qt * 64 + (qp * 2 + t) * 16 + l15] = sc[t];
        }
    }

    // ---- l: sum over this wave's 16 key-cols, stash per fh-half ----------
#pragma unroll
    for (int t = 0; t < 2; ++t)
#pragma unroll
        for (int r = 0; r < 4; ++r) {
            lsum[t][r] += __shfl_xor(lsum[t][r], 1, 64);
            lsum[t][r] += __shfl_xor(lsum[t][r], 2, 64);
            lsum[t][r] += __shfl_xor(lsum[t][r], 4, 64);
            lsum[t][r] += __shfl_xor(lsum[t][r], 8, 64);
        }
    if (l15 == 0) {
#pragma unroll
        for (int t = 0; t < 2; ++t)
#pragma unroll
            for (int r = 0; r < 4; ++r)
                l_lds[fh][(qp * 2 + t) * 16 + quad * 4 + r] = lsum[t][r];
    }
    __syncthreads();

    float* __restrict__ opart = ks ? o1 : o0;
    const size_t row0 = (size_t)b * T_ + qt * 64;

    if (tid < 64)
        __builtin_nontemporal_store(l_lds[0][tid] + l_lds[1][tid],
                                    &lpart[(size_t)ks * M_TOT + row0 + tid]);

#pragma unroll
    for (int t = 0; t < 2; ++t)
#pragma unroll
        for (int r = 0; r < 4; ++r) {
            const int qr = (qp * 2 + t) * 16 + quad * 4 + r;
#pragma unroll
            for (int ft = 0; ft < 8; ++ft)
                __builtin_nontemporal_store(
                    O[t][ft][r],
                    &opart[(row0 + qr) * F_ + fh * 128 + ft * 16 + l15]);
        }
}

// ---------------------------------------------------------------------------
// Kernel 6: combine split-K partials: out = (O0 + O1) / (l0 + l1)
// ---------------------------------------------------------------------------
__global__ __launch_bounds__(256) void combine_kernel(
    float* __restrict__ out_feat, const float* __restrict__ o1,
    const float* __restrict__ lpart)
{
    const size_t gid = (size_t)blockIdx.x * 256 + threadIdx.x;
    const size_t row = gid >> 6;
    const float inv = 1.0f / (lpart[row] + lpart[M_TOT + row]);
    floatx4 a  = __builtin_nontemporal_load(&((const floatx4*)out_feat)[gid]);
    floatx4 bx = __builtin_nontemporal_load(&((const floatx4*)o1)[gid]);
    a = (a + bx) * inv;
    __builtin_nontemporal_store(a, &((floatx4*)out_feat)[gid]);
}

extern "C" void kernel_launch(void* const* d_in, const int* in_sizes, int n_in,
                              void* d_out, int out_size, void* d_ws, size_t ws_size,
                              hipStream_t stream)
{
    const float* feat = (const float*)d_in[0];
    // d_in[1] = hlens (unused: reference overwrites peaks -> hlens_new = T)
    const float* Wq = (const float*)d_in[2];
    const float* bq = (const float*)d_in[3];
    const float* Wk = (const float*)d_in[4];
    const float* bk = (const float*)d_in[5];

    float* out_feat  = (float*)d_out;                       // [8,2048,256]
    float* out_hlens = out_feat + (size_t)M_TOT * F_;       // [8]
    float* out_score = out_hlens + B_;                      // [8,2048]

    short* qfh    = (short*)d_ws;                           // 8 MB
    short* qfl    = qfh + (size_t)M_TOT * F_;               // 8 MB
    short* stg    = qfl + (size_t)M_TOT * F_;               // 16 MB (kf+ff)
    short* wfqh   = stg + (size_t)2 * M_TOT * F_;           // 128 KB
    short* wfql   = wfqh + 65536;                           // 128 KB
    short* wfkh   = wfql + 65536;                           // 128 KB
    float* featpart = (float*)(wfkh + 65536);               // 512 KB
    float* kbar   = featpart + 131072;                      // 8 KB
    float* o1     = kbar + 2048;                            // 16 MB partial
    float* lpart  = featpart;                               // alias

    dim3 fgrid(65, B_);
    pack_feat_all<<<fgrid, 256, 0, stream>>>(feat, stg, featpart,
                                             Wq, Wk, wfqh, wfql, wfkh);

    proj_mfma<<<520, 512, 0, stream>>>(feat, wfqh, wfql, wfkh,
                                       bq, bk, qfh, qfl, stg,
                                       featpart, Wk, kbar, out_hlens);

    attn_mfma<<<512, 256, 0, stream>>>(qfh, qfl, stg, out_feat, o1, lpart,
                                       kbar, out_score);

    combine_kernel<<<M_TOT * F_ / 4 / 256, 256, 0, stream>>>(out_feat, o1, lpart);
}

// Round 11
// 173.694 us; speedup vs baseline: 1.1158x; 1.1158x over previous
//
#include <hip/hip_runtime.h>
#include <math.h>

#define B_ 8
#define T_ 2048
#define F_ 256
#define M_TOT (B_ * T_)   // 16384

typedef __attribute__((ext_vector_type(8))) short short8;
typedef __attribute__((ext_vector_type(4))) float floatx4;

// bf16 round-to-nearest-even helpers (finite inputs only)
__device__ __forceinline__ short f2bf(float x) {
    unsigned u = __float_as_uint(x);
    u += 0x7FFF + ((u >> 16) & 1);
    return (short)(u >> 16);
}
__device__ __forceinline__ float bf2f(short s) {
    return __uint_as_float(((unsigned)(unsigned short)s) << 16);
}

// async global -> LDS copy, 16 B per lane (gfx950 global_load_lds_dwordx4)
__device__ __forceinline__ void cp_g2l_16(const void* g, void* l) {
    __builtin_amdgcn_global_load_lds(
        (const __attribute__((address_space(1))) void*)g,
        (__attribute__((address_space(3))) void*)l, 16, 0, 0);
}

// ---------------------------------------------------------------------------
// Kernel 1: fused pre-pack. Blocks (0..63, b): one pass over feat producing
//  (a) A-fragments hi/lo for the projection GEMM (featAh/featAl, NT stores),
//  (b) PV B-fragments (hi) into the staged attn blocks (stg + 8192),
//  (c) per-(b,32-row-chunk) column sums (featpart, for kbar).
// Blocks (64, g): pack Wq (hi+lo) / Wk (hi) into B-fragment order.
// R20 note: R19 (proj self-transpose, featA eliminated) REGRESSED 19 µs —
// proj is latency/occupancy-shaped, not traffic-shaped. featA restored.
// ---------------------------------------------------------------------------
__global__ __launch_bounds__(256) void pack_feat_all(
    const float* __restrict__ feat,
    short* __restrict__ featAh, short* __restrict__ featAl,
    short* __restrict__ stg, float* __restrict__ featpart,
    const float* __restrict__ Wq, const float* __restrict__ Wk,
    short* __restrict__ wfqh, short* __restrict__ wfql,
    short* __restrict__ wfkh)
{
    const int tid = threadIdx.x;
    const int lane = tid & 63, w = tid >> 6;
    const int quad = lane >> 4, l15 = lane & 15;

    if (blockIdx.x == 64) {   // ---- W-pack blocks (8 x 256 thr) ----
#pragma unroll
        for (int i = 0; i < 8; ++i) {
            const int idx = blockIdx.y * 32 + w * 8 + i;   // 0..255
            const int isk = idx >> 7, nt = (idx >> 3) & 15, fc = idx & 7;
            const float* __restrict__ W = isk ? Wk : Wq;
            const int row = nt * 16 + l15, col = fc * 32 + quad * 8;
            float v[8];
            *(float4*)&v[0] = *(const float4*)&W[(size_t)row * F_ + col];
            *(float4*)&v[4] = *(const float4*)&W[(size_t)row * F_ + col + 4];
            const size_t dst = ((size_t)(nt * 8 + fc)) * 512 + lane * 8;
            if (isk) {
                short8 h;
#pragma unroll
                for (int j = 0; j < 8; ++j) h[j] = f2bf(v[j]);
                *(short8*)&wfkh[dst] = h;
            } else {
                short8 h, l;
#pragma unroll
                for (int j = 0; j < 8; ++j) {
                    const short hh = f2bf(v[j]);
                    h[j] = hh; l[j] = f2bf(v[j] - bf2f(hh));
                }
                *(short8*)&wfqh[dst] = h;
                *(short8*)&wfql[dst] = l;
            }
        }
        return;
    }

    __shared__ float lds[32][260];
    const int kc  = blockIdx.x;   // 0..63
    const int b   = blockIdx.y;

#pragma unroll
    for (int i = 0; i < 8; ++i) {
        const int lin = i * 256 + tid;
        const int r = lin >> 6, c4 = (lin & 63) * 4;
        float4 v = *(const float4*)&feat[((size_t)b * T_ + kc * 32 + r) * F_ + c4];
        lds[r][c4 + 0] = v.x; lds[r][c4 + 1] = v.y;
        lds[r][c4 + 2] = v.z; lds[r][c4 + 3] = v.w;
    }
    __syncthreads();

#pragma unroll
    for (int i = 0; i < 4; ++i) {
        const int idx = w * 4 + i;
        const int r16h = idx >> 3, fc = idx & 7;
        float v[8];
        *(float4*)&v[0] = *(const float4*)&lds[r16h * 16 + l15][fc * 32 + quad * 8];
        *(float4*)&v[4] = *(const float4*)&lds[r16h * 16 + l15][fc * 32 + quad * 8 + 4];
        short8 h, l;
#pragma unroll
        for (int j = 0; j < 8; ++j) {
            const short hh = f2bf(v[j]);
            h[j] = hh; l[j] = f2bf(v[j] - bf2f(hh));
        }
        const int r16 = b * 128 + kc * 2 + r16h;
        const size_t dst = ((size_t)r16 * 8 + fc) * 512 + lane * 8;
        __builtin_nontemporal_store(h, (short8*)&featAh[dst]);
        __builtin_nontemporal_store(l, (short8*)&featAl[dst]);
    }

#pragma unroll
    for (int fi = 0; fi < 4; ++fi) {
        const int ft = w + fi * 4;
        short8 h;
#pragma unroll
        for (int j = 0; j < 8; ++j)
            h[j] = f2bf(lds[quad * 8 + j][ft * 16 + l15]);
        const size_t dst = ((size_t)(b * 64 + kc)) * 16384 + 8192 + ft * 512 + lane * 8;
        *(short8*)&stg[dst] = h;
    }

    {
        float s = 0.f;
#pragma unroll
        for (int r = 0; r < 32; ++r) s += lds[r][tid];
        featpart[((size_t)b * 64 + kc) * 256 + tid] = s;
    }
}

// ---------------------------------------------------------------------------
// Kernel 4: MFMA projection straight into fragments (NT stores on outputs).
// XCD-coherent grid remap (R16): rg = x&127, ng = x>>7 -> the 4 blocks
// sharing one A row-group are on the same XCD, A fetched once per XCD.
// R18: wvec folded in as guard-blocks x >= 512 (batch = x-512): computes
// kbar = bk + Wk . mean_t(feat) from featpart, writes hlens. Uses wbuf as
// fp32 scratch. Blocks 0..511 unchanged -> XCD mapping preserved.
// ---------------------------------------------------------------------------
__global__ __launch_bounds__(512, 4) void proj_mfma(
    const short* __restrict__ featAh, const short* __restrict__ featAl,
    const short* __restrict__ wfqh, const short* __restrict__ wfql,
    const short* __restrict__ wfkh,
    const float* __restrict__ bq, const float* __restrict__ bk,
    short* __restrict__ qfh, short* __restrict__ qfl,
    short* __restrict__ stg,
    const float* __restrict__ featpart, const float* __restrict__ Wk,
    float* __restrict__ kbar_g, float* __restrict__ out_hlens)
{
    __shared__ short wbuf[2][8192];
    __shared__ float Tr[8][16][36];

    const int tid = threadIdx.x, lane = tid & 63, w = tid >> 6;
    const int quad = lane >> 4, l15 = lane & 15;
    const int x  = blockIdx.x;

    if (x >= 512) {   // ---- folded wvec blocks (8 x, only tid<256 active) --
        float* fb = (float*)wbuf;
        const int bb = x - 512;
        if (tid < 256) {
            float s = 0.f;
#pragma unroll 8
            for (int c = 0; c < 64; ++c)
                s += featpart[((size_t)bb * 64 + c) * 256 + tid];
            fb[tid] = s * (1.0f / (float)T_);
        }
        __syncthreads();
        if (tid < 256) {
            float acc = bk[tid];
#pragma unroll 8
            for (int f = 0; f < 256; ++f)
                acc += Wk[(size_t)tid * 256 + f] * fb[f];
            kbar_g[bb * 256 + tid] = acc;
        }
        if (bb == 0 && tid < B_) out_hlens[tid] = (float)T_;
        return;
    }

    const int ng = x >> 7, rg = x & 127;   // XCD-coherent remap
    const bool isq = ng < 2;
    const int r16 = rg * 8 + w;
    const int b = r16 >> 7, qt16 = r16 & 127;
    const int ntb = isq ? ng * 8 : (ng - 2) * 8;

    short8 ah[8], al[8];
#pragma unroll
    for (int fc = 0; fc < 8; ++fc) {
        const size_t off = ((size_t)r16 * 8 + fc) * 512 + lane * 8;
        ah[fc] = *(const short8*)&featAh[off];
        al[fc] = *(const short8*)&featAl[off];
    }

    const short* __restrict__ wsh = (isq ? wfqh : wfkh) + (size_t)ntb * 4096;
    const short* __restrict__ wsl = wfql + (size_t)ntb * 4096;
    const float* __restrict__ bias = isq ? bq : bk;

    cp_g2l_16(wsh + tid * 8, &wbuf[0][tid * 8]);
    if (isq) cp_g2l_16(wsl + tid * 8, &wbuf[0][4096 + tid * 8]);

    int cur = 0;
    for (int i = 0; i < 8; ++i, cur ^= 1) {
        __syncthreads();

        floatx4 C = (floatx4){0.f, 0.f, 0.f, 0.f};
#pragma unroll
        for (int fc = 0; fc < 8; ++fc) {
            short8 wh = *(const short8*)&wbuf[cur][fc * 512 + lane * 8];
            C = __builtin_amdgcn_mfma_f32_16x16x32_bf16(ah[fc], wh, C, 0, 0, 0);
            C = __builtin_amdgcn_mfma_f32_16x16x32_bf16(al[fc], wh, C, 0, 0, 0);
            if (isq) {
                short8 wl2 = *(const short8*)&wbuf[cur][4096 + fc * 512 + lane * 8];
                C = __builtin_amdgcn_mfma_f32_16x16x32_bf16(ah[fc], wl2, C, 0, 0, 0);
            }
        }

        if (i + 1 < 8) {
            cp_g2l_16(wsh + (size_t)(i + 1) * 4096 + tid * 8,
                      &wbuf[cur ^ 1][tid * 8]);
            if (isq) cp_g2l_16(wsl + (size_t)(i + 1) * 4096 + tid * 8,
                               &wbuf[cur ^ 1][4096 + tid * 8]);
        }

        const int nt = ntb + i;
        const float bv = bias[nt * 16 + l15];
        const int ch = (i & 1) * 16;
#pragma unroll
        for (int r = 0; r < 4; ++r)
            Tr[w][quad * 4 + r][ch + l15] = C[r] + bv;

        if (i & 1) {
            float v[8];
            *(float4*)&v[0] = *(const float4*)&Tr[w][l15][quad * 8];
            *(float4*)&v[4] = *(const float4*)&Tr[w][l15][quad * 8 + 4];
            const int p = nt >> 1;
            if (isq) {
                short8 h, l;
#pragma unroll
                for (int j = 0; j < 8; ++j) {
                    const short hh = f2bf(v[j]);
                    h[j] = hh; l[j] = f2bf(v[j] - bf2f(hh));
                }
                const size_t dst = ((size_t)(b * 8 + p) * 128 + qt16) * 512 + lane * 8;
                __builtin_nontemporal_store(h, (short8*)&qfh[dst]);
                __builtin_nontemporal_store(l, (short8*)&qfl[dst]);
            } else {
                short8 h;
#pragma unroll
                for (int j = 0; j < 8; ++j) h[j] = f2bf(v[j]);
                const size_t dst = ((size_t)(b * 64 + (qt16 >> 1))) * 16384
                                 + (p * 2 + (qt16 & 1)) * 512 + lane * 8;
                *(short8*)&stg[dst] = h;
            }
        }
    }
}

// ---------------------------------------------------------------------------
// Kernel 5: fused flash attention. Loop byte-identical to R10/R15/R16 (the
// 65.4 µs config) — every loop perturbation (R11-R14) regressed, and R17's
// fused combine thrashed L2 (partials = 4 MB/batch = full XCD L2). Epilogue
// has only the R16-proven score fusion; partials go out via NT stores and
// the separate combine_kernel handles the split-K merge.
// ---------------------------------------------------------------------------
__global__ __launch_bounds__(256, 2) void attn_mfma(
    const short* __restrict__ qfh_g, const short* __restrict__ qfl_g,
    const short* __restrict__ stg,
    float* __restrict__ o0, float* __restrict__ o1,
    float* __restrict__ lpart,
    const float* __restrict__ kbar_g, float* __restrict__ out_score)
{
    __shared__ short kbuf[2][16384];   // staged kt block: kf @0, ff @8192
    __shared__ float P_lds[64 * 36];   // [q][key], rows padded to 36 floats
    __shared__ float l_lds[2][64];     // [fh][q-row]

    const int tid  = threadIdx.x;
    const int wave = tid >> 6, lane = tid & 63;
    const int qp   = wave & 1, fh = wave >> 1;
    const int quad = lane >> 4, l15 = lane & 15;

    const int lid  = blockIdx.x;      // 0..511
    const int b    = lid & 7;         // XCD pin: batch -> XCD
    const int qt   = (lid >> 3) & 31;
    const int ks   = lid >> 8;

    // persistent Q fragments for TWO q-tiles (A-operand), hi/lo: 128 VGPRs
    short8 qh[2][8], ql[2][8];
#pragma unroll
    for (int t = 0; t < 2; ++t) {
        const int qt16 = qt * 4 + qp * 2 + t;
#pragma unroll
        for (int fc = 0; fc < 8; ++fc) {
            const size_t off = ((size_t)(b * 8 + fc) * 128 + qt16) * 512 + lane * 8;
            qh[t][fc] = *(const short8*)&qfh_g[off];
            ql[t][fc] = *(const short8*)&qfl_g[off];
        }
    }

    floatx4 O[2][8];
#pragma unroll
    for (int t = 0; t < 2; ++t)
#pragma unroll
        for (int i = 0; i < 8; ++i) O[t][i] = (floatx4){0.f, 0.f, 0.f, 0.f};
    float lsum[2][4] = {};

    const short* sbase = &stg[(size_t)b * 64 * 16384];
    const int kbeg = ks * 32, kend = kbeg + 32;

    {
        const short* src = sbase + (size_t)kbeg * 16384 + tid * 8;
        short* dst = &kbuf[0][tid * 8];
#pragma unroll
        for (int i = 0; i < 8; ++i)
            cp_g2l_16(src + i * 2048, dst + i * 2048);
    }

    int cur = 0;
    for (int kt = kbeg; kt < kend; ++kt, cur ^= 1) {
        __syncthreads();   // drains DMA for kbuf[cur]; P_lds readers done

        // ---- S: 2 q-tiles x this wave's 16-key half (slot = fh) ----------
        floatx4 Sa[2], Sb[2];
#pragma unroll
        for (int t = 0; t < 2; ++t) {
            Sa[t] = (floatx4){0.f, 0.f, 0.f, 0.f};
            Sb[t] = (floatx4){0.f, 0.f, 0.f, 0.f};
        }
#pragma unroll
        for (int fc = 0; fc < 8; ++fc) {
            short8 bh = *(const short8*)&kbuf[cur][(fc * 2 + fh) * 512 + lane * 8];
#pragma unroll
            for (int t = 0; t < 2; ++t) {
                Sa[t] = __builtin_amdgcn_mfma_f32_16x16x32_bf16(qh[t][fc], bh, Sa[t], 0, 0, 0);
                Sb[t] = __builtin_amdgcn_mfma_f32_16x16x32_bf16(ql[t][fc], bh, Sb[t], 0, 0, 0);
            }
        }

        // ---- exp (max-free) + write P [row][key] -------------------------
#pragma unroll
        for (int t = 0; t < 2; ++t)
#pragma unroll
            for (int r = 0; r < 4; ++r) {
                const float e = __expf(Sa[t][r] + Sb[t][r]);
                lsum[t][r] += e;
                P_lds[((qp * 2 + t) * 16 + quad * 4 + r) * 36 + fh * 16 + l15] = e;
            }
        __syncthreads();

        // ---- read P in A-layout (b128), convert to bf16 (hi only) --------
        short8 ph[2];
#pragma unroll
        for (int t = 0; t < 2; ++t) {
            float pv[8];
            *(float4*)&pv[0] = *(const float4*)&P_lds[((qp * 2 + t) * 16 + l15) * 36 + quad * 8];
            *(float4*)&pv[4] = *(const float4*)&P_lds[((qp * 2 + t) * 16 + l15) * 36 + quad * 8 + 4];
#pragma unroll
            for (int j = 0; j < 8; ++j)
                ph[t][j] = f2bf(pv[j]);
        }

        // ---- prefetch next kt into the other buffer (overlaps PV) --------
        if (kt + 1 < kend) {
            const short* src = sbase + (size_t)(kt + 1) * 16384 + tid * 8;
            short* dst = &kbuf[cur ^ 1][tid * 8];
#pragma unroll
            for (int i = 0; i < 8; ++i)
                cp_g2l_16(src + i * 2048, dst + i * 2048);
        }

        // ---- O += bf16(P) . fh  (2 q-tiles x wave's 128-f half) ----------
#pragma unroll
        for (int ft = 0; ft < 8; ++ft) {
            short8 fv = *(const short8*)&kbuf[cur][8192 + (fh * 8 + ft) * 512 + lane * 8];
#pragma unroll
            for (int t = 0; t < 2; ++t)
                O[t][ft] = __builtin_amdgcn_mfma_f32_16x16x32_bf16(ph[t], fv, O[t][ft], 0, 0, 0);
        }
    }

    // ---- score epilogue (ks==0 blocks): score[row] = (qh+ql) . kbar ------
    if (ks == 0) {
        const float* __restrict__ kb = &kbar_g[b * 256];
        float sc[2] = {0.f, 0.f};
#pragma unroll
        for (int fc = 0; fc < 8; ++fc) {
            float4 k0 = *(const float4*)&kb[fc * 32 + quad * 8];
            float4 k1 = *(const float4*)&kb[fc * 32 + quad * 8 + 4];
#pragma unroll
            for (int t = 0; t < 2; ++t) {
#pragma unroll
                for (int j = 0; j < 4; ++j) {
                    sc[t] += (bf2f(qh[t][fc][j]) + bf2f(ql[t][fc][j]))
                           * ((const float*)&k0)[j];
                    sc[t] += (bf2f(qh[t][fc][j + 4]) + bf2f(ql[t][fc][j + 4]))
                           * ((const float*)&k1)[j];
                }
            }
        }
#pragma unroll
        for (int t = 0; t < 2; ++t) {
            sc[t] += __shfl_xor(sc[t], 16, 64);
            sc[t] += __shfl_xor(sc[t], 32, 64);
            if (quad == 0)
                out_score[(size_t)b * T_ + qt * 64 + (qp * 2 + t) * 16 + l15] = sc[t];
        }
    }

    // ---- l: sum over this wave's 16 key-cols, stash per fh-half ----------
#pragma unroll
    for (int t = 0; t < 2; ++t)
#pragma unroll
        for (int r = 0; r < 4; ++r) {
            lsum[t][r] += __shfl_xor(lsum[t][r], 1, 64);
            lsum[t][r] += __shfl_xor(lsum[t][r], 2, 64);
            lsum[t][r] += __shfl_xor(lsum[t][r], 4, 64);
            lsum[t][r] += __shfl_xor(lsum[t][r], 8, 64);
        }
    if (l15 == 0) {
#pragma unroll
        for (int t = 0; t < 2; ++t)
#pragma unroll
            for (int r = 0; r < 4; ++r)
                l_lds[fh][(qp * 2 + t) * 16 + quad * 4 + r] = lsum[t][r];
    }
    __syncthreads();

    float* __restrict__ opart = ks ? o1 : o0;
    const size_t row0 = (size_t)b * T_ + qt * 64;

    if (tid < 64)
        __builtin_nontemporal_store(l_lds[0][tid] + l_lds[1][tid],
                                    &lpart[(size_t)ks * M_TOT + row0 + tid]);

#pragma unroll
    for (int t = 0; t < 2; ++t)
#pragma unroll
        for (int r = 0; r < 4; ++r) {
            const int qr = (qp * 2 + t) * 16 + quad * 4 + r;
#pragma unroll
            for (int ft = 0; ft < 8; ++ft)
                __builtin_nontemporal_store(
                    O[t][ft][r],
                    &opart[(row0 + qr) * F_ + fh * 128 + ft * 16 + l15]);
        }
}

// ---------------------------------------------------------------------------
// Kernel 6: combine split-K partials: out = (O0 + O1) / (l0 + l1)
// ---------------------------------------------------------------------------
__global__ __launch_bounds__(256) void combine_kernel(
    float* __restrict__ out_feat, const float* __restrict__ o1,
    const float* __restrict__ lpart)
{
    const size_t gid = (size_t)blockIdx.x * 256 + threadIdx.x;
    const size_t row = gid >> 6;
    const float inv = 1.0f / (lpart[row] + lpart[M_TOT + row]);
    floatx4 a  = __builtin_nontemporal_load(&((const floatx4*)out_feat)[gid]);
    floatx4 bx = __builtin_nontemporal_load(&((const floatx4*)o1)[gid]);
    a = (a + bx) * inv;
    __builtin_nontemporal_store(a, &((floatx4*)out_feat)[gid]);
}

extern "C" void kernel_launch(void* const* d_in, const int* in_sizes, int n_in,
                              void* d_out, int out_size, void* d_ws, size_t ws_size,
                              hipStream_t stream)
{
    const float* feat = (const float*)d_in[0];
    // d_in[1] = hlens (unused: reference overwrites peaks -> hlens_new = T)
    const float* Wq = (const float*)d_in[2];
    const float* bq = (const float*)d_in[3];
    const float* Wk = (const float*)d_in[4];
    const float* bk = (const float*)d_in[5];

    float* out_feat  = (float*)d_out;                       // [8,2048,256]
    float* out_hlens = out_feat + (size_t)M_TOT * F_;       // [8]
    float* out_score = out_hlens + B_;                      // [8,2048]

    short* featAh = (short*)d_ws;                           // 8 MB
    short* featAl = featAh + (size_t)M_TOT * F_;            // 8 MB
    short* qfh    = featAl + (size_t)M_TOT * F_;            // 8 MB
    short* qfl    = qfh + (size_t)M_TOT * F_;               // 8 MB
    short* stg    = qfl + (size_t)M_TOT * F_;               // 16 MB (kf+ff)
    short* wfqh   = stg + (size_t)2 * M_TOT * F_;           // 128 KB
    short* wfql   = wfqh + 65536;                           // 128 KB
    short* wfkh   = wfql + 65536;                           // 128 KB
    float* featpart = (float*)(wfkh + 65536);               // 512 KB
    float* kbar   = featpart + 131072;                      // 8 KB
    float* o1     = (float*)featAh;   // alias (16 MB region)
    float* lpart  = featpart;         // alias

    dim3 fgrid(65, B_);
    pack_feat_all<<<fgrid, 256, 0, stream>>>(feat, featAh, featAl, stg, featpart,
                                             Wq, Wk, wfqh, wfql, wfkh);

    proj_mfma<<<520, 512, 0, stream>>>(featAh, featAl, wfqh, wfql, wfkh,
                                       bq, bk, qfh, qfl, stg,
                                       featpart, Wk, kbar, out_hlens);

    attn_mfma<<<512, 256, 0, stream>>>(qfh, qfl, stg, out_feat, o1, lpart,
                                       kbar, out_score);

    combine_kernel<<<M_TOT * F_ / 4 / 256, 256, 0, stream>>>(out_feat, o1, lpart);
}